// Round 1
// baseline (289.549 us; speedup 1.0000x reference)
//
#include <hip/hip_runtime.h>
#include <math.h>

#define IN_DIM 16
#define HID 128
#define OUT_DIM 3
#define NEG 0.2f

__device__ __forceinline__ float lrelu(float a) { return a > 0.f ? a : NEG * a; }

// ---------------- tiny precompute: Wq/Wk folds --------------------
// wq1[r*16+d] = sum_c W1[(r*16+d)*128+c] * q1[c]   (32 outputs)
// wq2[r*128+d] = sum_c W2[(r*128+d)*3+c] * q2[c]   (256 outputs)
__global__ void k_wq(const float* __restrict__ W1, const float* __restrict__ q1,
                     const float* __restrict__ k1,
                     const float* __restrict__ W2, const float* __restrict__ q2,
                     const float* __restrict__ k2,
                     float* __restrict__ wq1, float* __restrict__ wk1,
                     float* __restrict__ wq2, float* __restrict__ wk2) {
    int t = threadIdx.x;  // 256 threads
    {
        const float* wrow = W2 + t * 3;
        wq2[t] = wrow[0] * q2[0] + wrow[1] * q2[1] + wrow[2] * q2[2];
        wk2[t] = wrow[0] * k2[0] + wrow[1] * k2[1] + wrow[2] * k2[2];
    }
    if (t < 32) {
        const float* wrow = W1 + t * HID;
        float aq = 0.f, ak = 0.f;
        for (int c = 0; c < HID; ++c) { float w = wrow[c]; aq += w * q1[c]; ak += w * k1[c]; }
        wq1[t] = aq; wk1[t] = ak;
    }
}

// ---------------- layer1 node transform: xr1[r][n][c] -------------
__global__ void __launch_bounds__(128) k_transform1(
    const float* __restrict__ x, const float* __restrict__ W1,
    float* __restrict__ xr1, int n_nodes, int nodes_per_block) {
    __shared__ float w[2 * IN_DIM * HID];   // 16 KiB
    __shared__ float xrow[IN_DIM];
    for (int i = threadIdx.x; i < 2 * IN_DIM * HID; i += 128) w[i] = W1[i];
    int n0 = blockIdx.x * nodes_per_block;
    int c = threadIdx.x;
    for (int g = 0; g < nodes_per_block; ++g) {
        int n = n0 + g;
        if (n >= n_nodes) break;
        __syncthreads();
        if (threadIdx.x < IN_DIM) xrow[threadIdx.x] = x[n * IN_DIM + threadIdx.x];
        __syncthreads();
        float a0 = 0.f, a1 = 0.f;
#pragma unroll
        for (int d = 0; d < IN_DIM; ++d) {
            float xv = xrow[d];
            a0 += xv * w[d * HID + c];
            a1 += xv * w[(IN_DIM + d) * HID + c];
        }
        xr1[((size_t)0 * n_nodes + n) * HID + c] = a0;
        xr1[((size_t)1 * n_nodes + n) * HID + c] = a1;
    }
}

// ---------------- layer1 per-node score scalars -------------------
__global__ void k_scores1(const float* __restrict__ x,
                          const float* __restrict__ wq1, const float* __restrict__ wk1,
                          float* __restrict__ sq1, float* __restrict__ sk1, int n_nodes) {
    int n = blockIdx.x * 256 + threadIdx.x;
    if (n >= n_nodes) return;
    float q0 = 0.f, q1v = 0.f, k0 = 0.f, k1v = 0.f;
#pragma unroll
    for (int d = 0; d < IN_DIM; ++d) {
        float xv = x[n * IN_DIM + d];
        q0 += xv * wq1[d]; q1v += xv * wq1[IN_DIM + d];
        k0 += xv * wk1[d]; k1v += xv * wk1[IN_DIM + d];
    }
    sq1[n] = q0; sq1[n_nodes + n] = q1v;
    sk1[n] = k0; sk1[n_nodes + n] = k1v;
}

// ---------------- CSR build ---------------------------------------
__global__ void k_hist(const int* __restrict__ dstp, int* __restrict__ counts, int ecnt) {
    int e = blockIdx.x * 256 + threadIdx.x;
    if (e >= ecnt) return;
    atomicAdd(&counts[dstp[e]], 1);
}

__global__ void k_scan1(const int* __restrict__ counts, int* __restrict__ exoff,
                        int* __restrict__ blockSums, int n) {
    __shared__ int s[512];
    int tid = threadIdx.x;
    int gid = blockIdx.x * 512 + tid;
    int v = (gid < n) ? counts[gid] : 0;
    s[tid] = v;
    __syncthreads();
    for (int off = 1; off < 512; off <<= 1) {
        int t = (tid >= off) ? s[tid - off] : 0;
        __syncthreads();
        s[tid] += t;
        __syncthreads();
    }
    if (gid < n) exoff[gid] = s[tid] - v;
    if (tid == 511) blockSums[blockIdx.x] = s[511];
}

__global__ void k_scan2(const int* __restrict__ blockSums, int* __restrict__ blockBase, int nblk) {
    __shared__ int s[128];
    int t = threadIdx.x;
    int v = (t < nblk) ? blockSums[t] : 0;
    s[t] = v;
    __syncthreads();
    for (int off = 1; off < 128; off <<= 1) {
        int u = (t >= off) ? s[t - off] : 0;
        __syncthreads();
        s[t] += u;
        __syncthreads();
    }
    if (t < nblk) blockBase[t] = s[t] - v;
}

__global__ void k_scan3(const int* __restrict__ exoff, const int* __restrict__ blockBase,
                        int* __restrict__ offsets, int n_nodes, int ecnt) {
    int i = blockIdx.x * 256 + threadIdx.x;
    if (i < n_nodes) offsets[i] = exoff[i] + blockBase[i >> 9];
    if (i == 0) offsets[n_nodes] = ecnt;
}

__global__ void k_scatter(const int* __restrict__ srcp, const int* __restrict__ dstp,
                          const int* __restrict__ etp, const int* __restrict__ offsets,
                          int* __restrict__ cursor, int* __restrict__ sorted, int ecnt) {
    int e = blockIdx.x * 256 + threadIdx.x;
    if (e >= ecnt) return;
    int d = dstp[e];
    int p = offsets[d] + atomicAdd(&cursor[d], 1);
    sorted[p] = (etp[e] << 16) | srcp[e];
}

// ---------------- layer1 aggregation (block per node) -------------
__global__ void __launch_bounds__(128) k_node1(
    const int* __restrict__ offsets, const int* __restrict__ sorted,
    const float* __restrict__ sq1, const float* __restrict__ sk1,
    const float* __restrict__ xr1, const float* __restrict__ b1,
    float* __restrict__ h, int n_nodes) {
    int n = blockIdx.x;
    int tid = threadIdx.x;  // = channel c
    int beg = offsets[n], end = offsets[n + 1];
    if (beg == end) { h[(size_t)n * HID + tid] = b1[tid]; return; }
    float s0 = sq1[n], s1 = sq1[n_nodes + n];
    __shared__ float red[HID];
    // phase 1: segment max (parallel over edges)
    float lmax = -INFINITY;
    for (int e = beg + tid; e < end; e += HID) {
        int pk = sorted[e];
        int et = pk >> 16, s = pk & 0xFFFF;
        float a = lrelu((et ? s1 : s0) + sk1[et * n_nodes + s]);
        lmax = fmaxf(lmax, a);
    }
    red[tid] = lmax;
    __syncthreads();
    for (int st = 64; st > 0; st >>= 1) {
        if (tid < st) red[tid] = fmaxf(red[tid], red[tid + st]);
        __syncthreads();
    }
    float m = red[0];
    // phase 2+3 fused: serial over edges; every thread owns channel tid
    float acc = 0.f, dsum = 0.f;
    for (int e = beg; e < end; ++e) {
        int pk = sorted[e];
        int et = pk >> 16, s = pk & 0xFFFF;
        float a = lrelu((et ? s1 : s0) + sk1[et * n_nodes + s]);
        float wgt = expf(a - m);
        dsum += wgt;
        acc += wgt * xr1[((size_t)et * n_nodes + s) * HID + tid];
    }
    h[(size_t)n * HID + tid] = acc / (dsum + 1e-16f) + b1[tid];
}

// ---------------- layer2 transform + scores -----------------------
__global__ void __launch_bounds__(256) k_transform2(
    const float* __restrict__ h, const float* __restrict__ W2,
    const float* __restrict__ wq2, const float* __restrict__ wk2,
    float* __restrict__ xr2, float* __restrict__ sq2, float* __restrict__ sk2,
    int n_nodes) {
    __shared__ float w[2 * HID * 3];
    __shared__ float wq[2 * HID], wk[2 * HID];
    for (int i = threadIdx.x; i < 2 * HID * 3; i += 256) w[i] = W2[i];
    { int i = threadIdx.x; wq[i] = wq2[i]; wk[i] = wk2[i]; }
    __syncthreads();
    int n = blockIdx.x * 256 + threadIdx.x;
    if (n >= n_nodes) return;
    float acc0 = 0, acc1 = 0, acc2 = 0, acc3 = 0, acc4 = 0, acc5 = 0;
    float q0 = 0, q1v = 0, k0 = 0, k1v = 0;
    const float4* hp = reinterpret_cast<const float4*>(h + (size_t)n * HID);
#pragma unroll 8
    for (int d4 = 0; d4 < HID / 4; ++d4) {
        float4 hv = hp[d4];
        float hh[4] = {hv.x, hv.y, hv.z, hv.w};
#pragma unroll
        for (int k = 0; k < 4; ++k) {
            int d = d4 * 4 + k;
            float v = hh[k];
            acc0 += v * w[d * 3 + 0]; acc1 += v * w[d * 3 + 1]; acc2 += v * w[d * 3 + 2];
            acc3 += v * w[(HID + d) * 3 + 0]; acc4 += v * w[(HID + d) * 3 + 1]; acc5 += v * w[(HID + d) * 3 + 2];
            q0 += v * wq[d]; q1v += v * wq[HID + d];
            k0 += v * wk[d]; k1v += v * wk[HID + d];
        }
    }
    float* x0 = xr2 + (size_t)n * 3;
    x0[0] = acc0; x0[1] = acc1; x0[2] = acc2;
    float* x1 = xr2 + ((size_t)n_nodes + n) * 3;
    x1[0] = acc3; x1[1] = acc4; x1[2] = acc5;
    sq2[n] = q0; sq2[n_nodes + n] = q1v;
    sk2[n] = k0; sk2[n_nodes + n] = k1v;
}

// ---------------- layer2 aggregation (wave per node) --------------
__global__ void __launch_bounds__(256) k_node2(
    const int* __restrict__ offsets, const int* __restrict__ sorted,
    const float* __restrict__ sq2, const float* __restrict__ sk2,
    const float* __restrict__ xr2, const float* __restrict__ b2,
    float* __restrict__ out, int n_nodes) {
    int gid = blockIdx.x * 256 + threadIdx.x;
    int n = gid >> 6;
    int lane = threadIdx.x & 63;
    if (n >= n_nodes) return;
    int beg = offsets[n], end = offsets[n + 1];
    if (beg == end) {
        if (lane < 3) out[(size_t)n * 3 + lane] = b2[lane];
        return;
    }
    float s0 = sq2[n], s1 = sq2[n_nodes + n];
    float lmax = -INFINITY;
    for (int e = beg + lane; e < end; e += 64) {
        int pk = sorted[e];
        int et = pk >> 16, s = pk & 0xFFFF;
        lmax = fmaxf(lmax, lrelu((et ? s1 : s0) + sk2[et * n_nodes + s]));
    }
    for (int off = 32; off; off >>= 1) lmax = fmaxf(lmax, __shfl_xor(lmax, off));
    float lsum = 0.f, a0 = 0.f, a1 = 0.f, a2 = 0.f;
    for (int e = beg + lane; e < end; e += 64) {
        int pk = sorted[e];
        int et = pk >> 16, s = pk & 0xFFFF;
        float a = lrelu((et ? s1 : s0) + sk2[et * n_nodes + s]);
        float wgt = expf(a - lmax);
        lsum += wgt;
        const float* xr = xr2 + ((size_t)et * n_nodes + s) * 3;
        a0 += wgt * xr[0]; a1 += wgt * xr[1]; a2 += wgt * xr[2];
    }
    for (int off = 32; off; off >>= 1) {
        lsum += __shfl_xor(lsum, off);
        a0 += __shfl_xor(a0, off);
        a1 += __shfl_xor(a1, off);
        a2 += __shfl_xor(a2, off);
    }
    if (lane == 0) {
        float inv = 1.f / (lsum + 1e-16f);
        out[(size_t)n * 3 + 0] = a0 * inv + b2[0];
        out[(size_t)n * 3 + 1] = a1 * inv + b2[1];
        out[(size_t)n * 3 + 2] = a2 * inv + b2[2];
    }
}

extern "C" void kernel_launch(void* const* d_in, const int* in_sizes, int n_in,
                              void* d_out, int out_size, void* d_ws, size_t ws_size,
                              hipStream_t stream) {
    const float* x  = (const float*)d_in[0];
    const int*   ei = (const int*)d_in[1];
    const int*   etp = (const int*)d_in[2];
    const float* W1 = (const float*)d_in[3];
    const float* q1 = (const float*)d_in[4];
    const float* k1 = (const float*)d_in[5];
    const float* b1 = (const float*)d_in[6];
    const float* W2 = (const float*)d_in[7];
    const float* q2 = (const float*)d_in[8];
    const float* k2 = (const float*)d_in[9];
    const float* b2 = (const float*)d_in[10];
    float* out = (float*)d_out;

    const int n_nodes = in_sizes[0] / IN_DIM;  // 50000
    const int ecnt    = in_sizes[2];           // 800000
    const int* srcp = ei;
    const int* dstp = ei + ecnt;

    // workspace carve-up (256B aligned)
    char* wp = (char*)d_ws;
    auto alloc = [&](size_t bytes) -> char* {
        char* p = wp;
        wp += (bytes + 255) & ~(size_t)255;
        return p;
    };
    float* xr1   = (float*)alloc((size_t)2 * n_nodes * HID * 4);
    float* hbuf  = (float*)alloc((size_t)n_nodes * HID * 4);
    float* xr2   = (float*)alloc((size_t)2 * n_nodes * 3 * 4);
    float* sq1   = (float*)alloc((size_t)2 * n_nodes * 4);
    float* sk1   = (float*)alloc((size_t)2 * n_nodes * 4);
    float* sq2   = (float*)alloc((size_t)2 * n_nodes * 4);
    float* sk2   = (float*)alloc((size_t)2 * n_nodes * 4);
    float* wq1   = (float*)alloc(32 * 4);
    float* wk1   = (float*)alloc(32 * 4);
    float* wq2   = (float*)alloc(256 * 4);
    float* wk2   = (float*)alloc(256 * 4);
    int* counts  = (int*)alloc((size_t)n_nodes * 4);
    int* exoff   = (int*)alloc((size_t)n_nodes * 4);
    int* blockSums = (int*)alloc(512);
    int* blockBase = (int*)alloc(512);
    int* offsets = (int*)alloc((size_t)(n_nodes + 1) * 4);
    int* cursor  = (int*)alloc((size_t)n_nodes * 4);
    int* sorted  = (int*)alloc((size_t)ecnt * 4);

    const int NPB = 64;  // nodes per block in transform1
    int nblk_scan = (n_nodes + 511) / 512;

    hipMemsetAsync(counts, 0, (size_t)n_nodes * 4, stream);
    hipMemsetAsync(cursor, 0, (size_t)n_nodes * 4, stream);

    k_wq<<<1, 256, 0, stream>>>(W1, q1, k1, W2, q2, k2, wq1, wk1, wq2, wk2);
    k_transform1<<<(n_nodes + NPB - 1) / NPB, 128, 0, stream>>>(x, W1, xr1, n_nodes, NPB);
    k_scores1<<<(n_nodes + 255) / 256, 256, 0, stream>>>(x, wq1, wk1, sq1, sk1, n_nodes);

    k_hist<<<(ecnt + 255) / 256, 256, 0, stream>>>(dstp, counts, ecnt);
    k_scan1<<<nblk_scan, 512, 0, stream>>>(counts, exoff, blockSums, n_nodes);
    k_scan2<<<1, 128, 0, stream>>>(blockSums, blockBase, nblk_scan);
    k_scan3<<<(n_nodes + 256) / 256, 256, 0, stream>>>(exoff, blockBase, offsets, n_nodes, ecnt);
    k_scatter<<<(ecnt + 255) / 256, 256, 0, stream>>>(srcp, dstp, etp, offsets, cursor, sorted, ecnt);

    k_node1<<<n_nodes, 128, 0, stream>>>(offsets, sorted, sq1, sk1, xr1, b1, hbuf, n_nodes);

    k_transform2<<<(n_nodes + 255) / 256, 256, 0, stream>>>(hbuf, W2, wq2, wk2, xr2, sq2, sk2, n_nodes);
    k_node2<<<(n_nodes * 64 + 255) / 256, 256, 0, stream>>>(offsets, sorted, sq2, sk2, xr2, b2, out, n_nodes);
}

// Round 3
// 182.489 us; speedup vs baseline: 1.5867x; 1.5867x over previous
//
#include <hip/hip_runtime.h>
#include <math.h>

#define IN_DIM 16
#define HID 128
#define OUT_DIM 3
#define NEG 0.2f

__device__ __forceinline__ float lrelu(float a) { return a > 0.f ? a : NEG * a; }

// ---------------- tiny precompute: Wq/Wk folds --------------------
__global__ void k_wq(const float* __restrict__ W1, const float* __restrict__ q1,
                     const float* __restrict__ k1,
                     const float* __restrict__ W2, const float* __restrict__ q2,
                     const float* __restrict__ k2,
                     float* __restrict__ wq1, float* __restrict__ wk1,
                     float* __restrict__ wq2, float* __restrict__ wk2) {
    int t = threadIdx.x;  // 256 threads
    {
        const float* wrow = W2 + t * 3;
        wq2[t] = wrow[0] * q2[0] + wrow[1] * q2[1] + wrow[2] * q2[2];
        wk2[t] = wrow[0] * k2[0] + wrow[1] * k2[1] + wrow[2] * k2[2];
    }
    if (t < 32) {
        const float* wrow = W1 + t * HID;
        float aq = 0.f, ak = 0.f;
        for (int c = 0; c < HID; ++c) { float w = wrow[c]; aq += w * q1[c]; ak += w * k1[c]; }
        wq1[t] = aq; wk1[t] = ak;
    }
}

// ---------------- fused: layer1 score scalars + dst histogram(+rank)
__global__ void __launch_bounds__(256) k_prep(
    const float* __restrict__ x,
    const float* __restrict__ wq1, const float* __restrict__ wk1,
    float* __restrict__ sq1, float* __restrict__ sk1,
    const int* __restrict__ dstp, int* __restrict__ counts, int* __restrict__ rank,
    int n_nodes, int ecnt) {
    __shared__ float wq[2 * IN_DIM], wk[2 * IN_DIM];
    if (threadIdx.x < 2 * IN_DIM) { wq[threadIdx.x] = wq1[threadIdx.x]; wk[threadIdx.x] = wk1[threadIdx.x]; }
    __syncthreads();
    int gid = blockIdx.x * 256 + threadIdx.x;
    if (gid < ecnt) rank[gid] = atomicAdd(&counts[dstp[gid]], 1);
    if (gid < n_nodes) {
        float q0 = 0.f, q1v = 0.f, k0 = 0.f, k1v = 0.f;
        const float4* xp = reinterpret_cast<const float4*>(x + (size_t)gid * IN_DIM);
#pragma unroll
        for (int d4 = 0; d4 < IN_DIM / 4; ++d4) {
            float4 v = xp[d4];
            float vv[4] = {v.x, v.y, v.z, v.w};
#pragma unroll
            for (int j = 0; j < 4; ++j) {
                int d = d4 * 4 + j;
                q0 += vv[j] * wq[d]; q1v += vv[j] * wq[IN_DIM + d];
                k0 += vv[j] * wk[d]; k1v += vv[j] * wk[IN_DIM + d];
            }
        }
        sq1[gid] = q0; sq1[n_nodes + gid] = q1v;
        sk1[gid] = k0; sk1[n_nodes + gid] = k1v;
    }
}

// ---------------- scan over counts -> offsets ---------------------
__global__ void k_scan1(const int* __restrict__ counts, int* __restrict__ exoff,
                        int* __restrict__ blockSums, int n) {
    __shared__ int s[512];
    int tid = threadIdx.x;
    int gid = blockIdx.x * 512 + tid;
    int v = (gid < n) ? counts[gid] : 0;
    s[tid] = v;
    __syncthreads();
    for (int off = 1; off < 512; off <<= 1) {
        int t = (tid >= off) ? s[tid - off] : 0;
        __syncthreads();
        s[tid] += t;
        __syncthreads();
    }
    if (gid < n) exoff[gid] = s[tid] - v;
    if (tid == 511) blockSums[blockIdx.x] = s[511];
}

__global__ void k_scan2(const int* __restrict__ blockSums, int* __restrict__ blockBase, int nblk) {
    __shared__ int s[128];
    int t = threadIdx.x;
    int v = (t < nblk) ? blockSums[t] : 0;
    s[t] = v;
    __syncthreads();
    for (int off = 1; off < 128; off <<= 1) {
        int u = (t >= off) ? s[t - off] : 0;
        __syncthreads();
        s[t] += u;
        __syncthreads();
    }
    if (t < nblk) blockBase[t] = s[t] - v;
}

__global__ void k_scan3(const int* __restrict__ exoff, const int* __restrict__ blockBase,
                        int* __restrict__ offsets, int n_nodes, int ecnt) {
    int i = blockIdx.x * 256 + threadIdx.x;
    if (i < n_nodes) offsets[i] = exoff[i] + blockBase[i >> 9];
    if (i == 0) offsets[n_nodes] = ecnt;
}

// ---------------- scatter edges into CSR order (rank precomputed) -
__global__ void __launch_bounds__(256) k_scatter(
    const int* __restrict__ srcp, const int* __restrict__ dstp,
    const int* __restrict__ etp, const int* __restrict__ offsets,
    const int* __restrict__ rank, int* __restrict__ sorted, int ecnt) {
    int e = blockIdx.x * 256 + threadIdx.x;
    if (e >= ecnt) return;
    int d = dstp[e];
    sorted[offsets[d] + rank[e]] = (etp[e] << 16) | srcp[e];
}

// ---------------- layer1: aggregate-then-transform ----------------
// wave per node (4 nodes / 256-thread block). 16-dim aggregation per
// relation, then 16x128 transform per relation from LDS weights.
__global__ void __launch_bounds__(256) k_node1(
    const int* __restrict__ offsets, const int* __restrict__ sorted,
    const float* __restrict__ sq1, const float* __restrict__ sk1,
    const float* __restrict__ x, const float* __restrict__ W1,
    const float* __restrict__ b1, float* __restrict__ h, int n_nodes) {
    __shared__ float w[2 * IN_DIM * HID];  // 16 KiB
    for (int i = threadIdx.x; i < 2 * IN_DIM * HID; i += 256) w[i] = W1[i];
    __syncthreads();
    int wid = threadIdx.x >> 6;
    int lane = threadIdx.x & 63;
    int n = blockIdx.x * 4 + wid;
    if (n >= n_nodes) return;
    int beg = offsets[n], end = offsets[n + 1];
    float s0 = sq1[n], s1 = sq1[n_nodes + n];

    // phase 1: segment max (lane-parallel over edges)
    float lm = -INFINITY;
    for (int e = beg + lane; e < end; e += 64) {
        int pk = sorted[e];
        int et = pk >> 16, s = pk & 0xFFFF;
        lm = fmaxf(lm, lrelu((et ? s1 : s0) + sk1[et * n_nodes + s]));
    }
#pragma unroll
    for (int off = 32; off; off >>= 1) lm = fmaxf(lm, __shfl_xor(lm, off));
    float m = lm;

    // phase 2: 16-dim weighted aggregation per relation.
    // lane layout: d = lane&15 (channel), j = lane>>4 (edge slot, 4-way)
    int d = lane & 15, j = lane >> 4;
    float a0 = 0.f, a1 = 0.f, ds = 0.f;
    for (int e = beg + j; e < end; e += 4) {
        int pk = sorted[e];
        int et = pk >> 16, s = pk & 0xFFFF;
        float alpha = lrelu((et ? s1 : s0) + sk1[et * n_nodes + s]);
        float wgt = __expf(alpha - m);
        ds += wgt;
        float xv = x[s * IN_DIM + d];  // 16-lane group: 64B coalesced, L2-resident
        if (et == 0) a0 += wgt * xv; else a1 += wgt * xv;
    }
    // reduce across the 4 edge-slot groups: xor 16 and 32 combine lanes
    // with the SAME channel d in different groups j. After this, every
    // lane holds the full segment sums for its channel; ds is the exact
    // softmax denominator (no within-group double-count: xor16/32 never
    // pairs two lanes of the same group).
#pragma unroll
    for (int off = 16; off <= 32; off <<= 1) {
        a0 += __shfl_xor(a0, off);
        a1 += __shfl_xor(a1, off);
        ds += __shfl_xor(ds, off);
    }
    float inv = 1.f / (ds + 1e-16f);
    a0 *= inv; a1 *= inv;

    // phase 3: out[c] = sum_d A0[d] W[0,d,c] + A1[d] W[1,d,c]  (+bias)
    float o0 = 0.f, o1 = 0.f;
#pragma unroll
    for (int dp = 0; dp < IN_DIM; ++dp) {
        float A0 = __shfl(a0, dp);
        float A1 = __shfl(a1, dp);
        o0 += A0 * w[dp * HID + lane]      + A1 * w[2048 + dp * HID + lane];
        o1 += A0 * w[dp * HID + 64 + lane] + A1 * w[2048 + dp * HID + 64 + lane];
    }
    h[(size_t)n * HID + lane]      = o0 + b1[lane];
    h[(size_t)n * HID + 64 + lane] = o1 + b1[64 + lane];
}

// ---------------- layer2 transform + scores (wave per node) -------
__global__ void __launch_bounds__(256) k_transform2(
    const float* __restrict__ h, const float* __restrict__ W2,
    const float* __restrict__ wq2, const float* __restrict__ wk2,
    float* __restrict__ xr2p, float* __restrict__ sq2, float* __restrict__ sk2,
    int n_nodes) {
    __shared__ float ws[2 * HID * 3];   // 768
    __shared__ float wqs[2 * HID], wks[2 * HID];
    for (int i = threadIdx.x; i < 2 * HID * 3; i += 256) ws[i] = W2[i];
    { int i = threadIdx.x; wqs[i] = wq2[i]; wks[i] = wk2[i]; }
    __syncthreads();
    int wid = threadIdx.x >> 6;
    int lane = threadIdx.x & 63;
    int n = blockIdx.x * 4 + wid;
    if (n >= n_nodes) return;
    float hv0 = h[(size_t)n * HID + lane];
    float hv1 = h[(size_t)n * HID + 64 + lane];
    float p00 = hv0 * ws[lane * 3 + 0] + hv1 * ws[(64 + lane) * 3 + 0];
    float p01 = hv0 * ws[lane * 3 + 1] + hv1 * ws[(64 + lane) * 3 + 1];
    float p02 = hv0 * ws[lane * 3 + 2] + hv1 * ws[(64 + lane) * 3 + 2];
    float p10 = hv0 * ws[384 + lane * 3 + 0] + hv1 * ws[384 + (64 + lane) * 3 + 0];
    float p11 = hv0 * ws[384 + lane * 3 + 1] + hv1 * ws[384 + (64 + lane) * 3 + 1];
    float p12 = hv0 * ws[384 + lane * 3 + 2] + hv1 * ws[384 + (64 + lane) * 3 + 2];
    float q0 = hv0 * wqs[lane] + hv1 * wqs[64 + lane];
    float q1 = hv0 * wqs[HID + lane] + hv1 * wqs[HID + 64 + lane];
    float k0 = hv0 * wks[lane] + hv1 * wks[64 + lane];
    float k1 = hv0 * wks[HID + lane] + hv1 * wks[HID + 64 + lane];
#pragma unroll
    for (int off = 32; off; off >>= 1) {
        p00 += __shfl_xor(p00, off); p01 += __shfl_xor(p01, off); p02 += __shfl_xor(p02, off);
        p10 += __shfl_xor(p10, off); p11 += __shfl_xor(p11, off); p12 += __shfl_xor(p12, off);
        q0 += __shfl_xor(q0, off);   q1 += __shfl_xor(q1, off);
        k0 += __shfl_xor(k0, off);   k1 += __shfl_xor(k1, off);
    }
    if (lane == 0) {
        float4* r0 = reinterpret_cast<float4*>(xr2p + (size_t)n * 4);
        float4* r1 = reinterpret_cast<float4*>(xr2p + ((size_t)n_nodes + n) * 4);
        *r0 = make_float4(p00, p01, p02, 0.f);
        *r1 = make_float4(p10, p11, p12, 0.f);
        sq2[n] = q0; sq2[n_nodes + n] = q1;
        sk2[n] = k0; sk2[n_nodes + n] = k1;
    }
}

// ---------------- layer2 aggregation (16 lanes per node) ----------
__global__ void __launch_bounds__(256) k_node2(
    const int* __restrict__ offsets, const int* __restrict__ sorted,
    const float* __restrict__ sq2, const float* __restrict__ sk2,
    const float* __restrict__ xr2p, const float* __restrict__ b2,
    float* __restrict__ out, int n_nodes) {
    int gid = blockIdx.x * 256 + threadIdx.x;
    int n = gid >> 4;
    int l = threadIdx.x & 15;
    if (n >= n_nodes) return;
    int beg = offsets[n], end = offsets[n + 1];
    if (beg == end) {
        if (l < 3) out[(size_t)n * 3 + l] = b2[l];
        return;
    }
    float s0 = sq2[n], s1 = sq2[n_nodes + n];
    float lm = -INFINITY;
    for (int e = beg + l; e < end; e += 16) {
        int pk = sorted[e];
        int et = pk >> 16, s = pk & 0xFFFF;
        lm = fmaxf(lm, lrelu((et ? s1 : s0) + sk2[et * n_nodes + s]));
    }
#pragma unroll
    for (int off = 8; off; off >>= 1) lm = fmaxf(lm, __shfl_xor(lm, off));
    float lsum = 0.f, a0 = 0.f, a1 = 0.f, a2 = 0.f;
    for (int e = beg + l; e < end; e += 16) {
        int pk = sorted[e];
        int et = pk >> 16, s = pk & 0xFFFF;
        float a = lrelu((et ? s1 : s0) + sk2[et * n_nodes + s]);
        float wgt = __expf(a - lm);
        lsum += wgt;
        const float4 xr = *reinterpret_cast<const float4*>(xr2p + ((size_t)et * n_nodes + s) * 4);
        a0 += wgt * xr.x; a1 += wgt * xr.y; a2 += wgt * xr.z;
    }
#pragma unroll
    for (int off = 8; off; off >>= 1) {
        lsum += __shfl_xor(lsum, off);
        a0 += __shfl_xor(a0, off);
        a1 += __shfl_xor(a1, off);
        a2 += __shfl_xor(a2, off);
    }
    if (l == 0) {
        float inv = 1.f / (lsum + 1e-16f);
        out[(size_t)n * 3 + 0] = a0 * inv + b2[0];
        out[(size_t)n * 3 + 1] = a1 * inv + b2[1];
        out[(size_t)n * 3 + 2] = a2 * inv + b2[2];
    }
}

extern "C" void kernel_launch(void* const* d_in, const int* in_sizes, int n_in,
                              void* d_out, int out_size, void* d_ws, size_t ws_size,
                              hipStream_t stream) {
    const float* x  = (const float*)d_in[0];
    const int*   ei = (const int*)d_in[1];
    const int*   etp = (const int*)d_in[2];
    const float* W1 = (const float*)d_in[3];
    const float* q1 = (const float*)d_in[4];
    const float* k1 = (const float*)d_in[5];
    const float* b1 = (const float*)d_in[6];
    const float* W2 = (const float*)d_in[7];
    const float* q2 = (const float*)d_in[8];
    const float* k2 = (const float*)d_in[9];
    const float* b2 = (const float*)d_in[10];
    float* out = (float*)d_out;

    const int n_nodes = in_sizes[0] / IN_DIM;  // 50000
    const int ecnt    = in_sizes[2];           // 800000
    const int* srcp = ei;
    const int* dstp = ei + ecnt;

    char* wp = (char*)d_ws;
    auto alloc = [&](size_t bytes) -> char* {
        char* p = wp;
        wp += (bytes + 255) & ~(size_t)255;
        return p;
    };
    float* hbuf  = (float*)alloc((size_t)n_nodes * HID * 4);
    float* xr2p  = (float*)alloc((size_t)2 * n_nodes * 4 * 4);
    float* sq1   = (float*)alloc((size_t)2 * n_nodes * 4);
    float* sk1   = (float*)alloc((size_t)2 * n_nodes * 4);
    float* sq2   = (float*)alloc((size_t)2 * n_nodes * 4);
    float* sk2   = (float*)alloc((size_t)2 * n_nodes * 4);
    float* wq1   = (float*)alloc(32 * 4);
    float* wk1   = (float*)alloc(32 * 4);
    float* wq2   = (float*)alloc(256 * 4);
    float* wk2   = (float*)alloc(256 * 4);
    int* counts  = (int*)alloc((size_t)n_nodes * 4);
    int* exoff   = (int*)alloc((size_t)n_nodes * 4);
    int* blockSums = (int*)alloc(512);
    int* blockBase = (int*)alloc(512);
    int* offsets = (int*)alloc((size_t)(n_nodes + 1) * 4);
    int* rank    = (int*)alloc((size_t)ecnt * 4);
    int* sorted  = (int*)alloc((size_t)ecnt * 4);

    int nblk_scan = (n_nodes + 511) / 512;
    int eblk = (ecnt + 255) / 256;

    hipMemsetAsync(counts, 0, (size_t)n_nodes * 4, stream);

    k_wq<<<1, 256, 0, stream>>>(W1, q1, k1, W2, q2, k2, wq1, wk1, wq2, wk2);
    k_prep<<<eblk, 256, 0, stream>>>(x, wq1, wk1, sq1, sk1, dstp, counts, rank, n_nodes, ecnt);
    k_scan1<<<nblk_scan, 512, 0, stream>>>(counts, exoff, blockSums, n_nodes);
    k_scan2<<<1, 128, 0, stream>>>(blockSums, blockBase, nblk_scan);
    k_scan3<<<(n_nodes + 256) / 256, 256, 0, stream>>>(exoff, blockBase, offsets, n_nodes, ecnt);
    k_scatter<<<eblk, 256, 0, stream>>>(srcp, dstp, etp, offsets, rank, sorted, ecnt);

    k_node1<<<(n_nodes + 3) / 4, 256, 0, stream>>>(offsets, sorted, sq1, sk1, x, W1, b1, hbuf, n_nodes);
    k_transform2<<<(n_nodes + 3) / 4, 256, 0, stream>>>(hbuf, W2, wq2, wk2, xr2p, sq2, sk2, n_nodes);
    k_node2<<<(n_nodes * 16 + 255) / 256, 256, 0, stream>>>(offsets, sorted, sq2, sk2, xr2p, b2, out, n_nodes);
}

// Round 5
// 148.267 us; speedup vs baseline: 1.9529x; 1.2308x over previous
//
#include <hip/hip_runtime.h>
#include <math.h>

#define IN_DIM 16
#define HID 128
#define NEG 0.2f

__device__ __forceinline__ float lrelu(float a) { return a > 0.f ? a : NEG * a; }

// ---------------- precompute: wq1/wk1, M[32][10], C[10] -----------
// A (32-dim per node) = per-relation softmax-weighted input sums.
// h = A·W1flat + b1;  layer-2 needs only [xr2_r0(3) xr2_r1(3) sq2(2) sk2(2)]
// = A·M + C  with  M[dp][o] = sum_c W1[dp][c]·T[c][o],  C[o] = sum_c b1[c]·T[c][o]
// T[c][0..2]=W2[0][c][:], T[c][3..5]=W2[1][c][:], T[c][6..7]=W2[r]q2, T[c][8..9]=W2[r]k2
__global__ void __launch_bounds__(512) k_pre(
    const float* __restrict__ W1, const float* __restrict__ q1, const float* __restrict__ k1,
    const float* __restrict__ b1, const float* __restrict__ W2, const float* __restrict__ q2,
    const float* __restrict__ k2,
    float* __restrict__ wq1, float* __restrict__ wk1,
    float* __restrict__ M, float* __restrict__ C) {
    __shared__ float wq2l[256], wk2l[256];   // [r*128+c]
    int t = threadIdx.x;
    if (t < 256) {
        const float* wrow = W2 + t * 3;      // t = r*128+c  -> W2[r][c][:]
        wq2l[t] = wrow[0] * q2[0] + wrow[1] * q2[1] + wrow[2] * q2[2];
        wk2l[t] = wrow[0] * k2[0] + wrow[1] * k2[1] + wrow[2] * k2[2];
    } else if (t < 288) {
        int i = t - 256;                     // i = r*16+d
        const float* wrow = W1 + i * HID;
        float aq = 0.f, ak = 0.f;
        for (int c = 0; c < HID; ++c) { float w = wrow[c]; aq += w * q1[c]; ak += w * k1[c]; }
        wq1[i] = aq; wk1[i] = ak;
    }
    __syncthreads();
    auto T = [&](int c, int o) -> float {
        if (o < 3) return W2[c * 3 + o];
        if (o < 6) return W2[384 + c * 3 + (o - 3)];
        if (o == 6) return wq2l[c];
        if (o == 7) return wq2l[128 + c];
        if (o == 8) return wk2l[c];
        return wk2l[128 + c];
    };
    if (t < 320) {
        int dp = t / 10, o = t % 10;
        const float* wrow = W1 + dp * HID;
        float acc = 0.f;
        for (int c = 0; c < HID; ++c) acc += wrow[c] * T(c, o);
        M[dp * 10 + o] = acc;
    } else if (t < 330) {
        int o = t - 320;
        float acc = 0.f;
        for (int c = 0; c < HID; ++c) acc += b1[c] * T(c, o);
        C[o] = acc;
    }
}

// ---------------- fused: layer1 score scalars + dst histogram(+rank)
__global__ void __launch_bounds__(256) k_prep(
    const float* __restrict__ x,
    const float* __restrict__ wq1, const float* __restrict__ wk1,
    float* __restrict__ sq1, float* __restrict__ sk1,
    const int* __restrict__ dstp, int* __restrict__ counts, int* __restrict__ rank,
    int n_nodes, int ecnt) {
    __shared__ float wq[2 * IN_DIM], wk[2 * IN_DIM];
    if (threadIdx.x < 2 * IN_DIM) { wq[threadIdx.x] = wq1[threadIdx.x]; wk[threadIdx.x] = wk1[threadIdx.x]; }
    __syncthreads();
    int gid = blockIdx.x * 256 + threadIdx.x;
    if (gid < ecnt) rank[gid] = atomicAdd(&counts[dstp[gid]], 1);
    if (gid < n_nodes) {
        float q0 = 0.f, q1v = 0.f, k0 = 0.f, k1v = 0.f;
        const float4* xp = reinterpret_cast<const float4*>(x + (size_t)gid * IN_DIM);
#pragma unroll
        for (int d4 = 0; d4 < IN_DIM / 4; ++d4) {
            float4 v = xp[d4];
            float vv[4] = {v.x, v.y, v.z, v.w};
#pragma unroll
            for (int j = 0; j < 4; ++j) {
                int d = d4 * 4 + j;
                q0 += vv[j] * wq[d]; q1v += vv[j] * wq[IN_DIM + d];
                k0 += vv[j] * wk[d]; k1v += vv[j] * wk[IN_DIM + d];
            }
        }
        sq1[gid] = q0; sq1[n_nodes + gid] = q1v;
        sk1[gid] = k0; sk1[n_nodes + gid] = k1v;
    }
}

// ---------------- scan over counts -> offsets ---------------------
__global__ void k_scan1(const int* __restrict__ counts, int* __restrict__ exoff,
                        int* __restrict__ blockSums, int n) {
    __shared__ int s[512];
    int tid = threadIdx.x;
    int gid = blockIdx.x * 512 + tid;
    int v = (gid < n) ? counts[gid] : 0;
    s[tid] = v;
    __syncthreads();
    for (int off = 1; off < 512; off <<= 1) {
        int t = (tid >= off) ? s[tid - off] : 0;
        __syncthreads();
        s[tid] += t;
        __syncthreads();
    }
    if (gid < n) exoff[gid] = s[tid] - v;
    if (tid == 511) blockSums[blockIdx.x] = s[511];
}

__global__ void k_scan2(const int* __restrict__ blockSums, int* __restrict__ blockBase, int nblk) {
    __shared__ int s[128];
    int t = threadIdx.x;
    int v = (t < nblk) ? blockSums[t] : 0;
    s[t] = v;
    __syncthreads();
    for (int off = 1; off < 128; off <<= 1) {
        int u = (t >= off) ? s[t - off] : 0;
        __syncthreads();
        s[t] += u;
        __syncthreads();
    }
    if (t < nblk) blockBase[t] = s[t] - v;
}

__global__ void k_scan3(const int* __restrict__ exoff, const int* __restrict__ blockBase,
                        int* __restrict__ offsets, int n_nodes, int ecnt) {
    int i = blockIdx.x * 256 + threadIdx.x;
    if (i < n_nodes) offsets[i] = exoff[i] + blockBase[i >> 9];
    if (i == 0) offsets[n_nodes] = ecnt;
}

// ---------------- scatter edges into CSR order --------------------
__global__ void __launch_bounds__(256) k_scatter(
    const int* __restrict__ srcp, const int* __restrict__ dstp,
    const int* __restrict__ etp, const int* __restrict__ offsets,
    const int* __restrict__ rank, int* __restrict__ sorted, int ecnt) {
    int e = blockIdx.x * 256 + threadIdx.x;
    if (e >= ecnt) return;
    int d = dstp[e];
    sorted[offsets[d] + rank[e]] = (etp[e] << 16) | srcp[e];
}

// ---------------- layer1 fused: aggregate -> 10 outputs -----------
// wave per node; single edge pass (no max subtraction: |alpha| << 88).
__global__ void __launch_bounds__(256) k_layer1(
    const int* __restrict__ offsets, const int* __restrict__ sorted,
    const float* __restrict__ sq1, const float* __restrict__ sk1,
    const float* __restrict__ x, const float* __restrict__ M, const float* __restrict__ C,
    float* __restrict__ xr2p, float* __restrict__ sq2, float* __restrict__ sk2,
    int n_nodes) {
    __shared__ float Ml[320], Cl[10];
    __shared__ float Al[4][32];
    for (int i = threadIdx.x; i < 320; i += 256) Ml[i] = M[i];   // FIX: 320 > blockDim
    if (threadIdx.x < 10)  Cl[threadIdx.x] = C[threadIdx.x];
    __syncthreads();
    int wid = threadIdx.x >> 6, lane = threadIdx.x & 63;
    int n = blockIdx.x * 4 + wid;
    if (n >= n_nodes) return;
    int beg = offsets[n], end = offsets[n + 1];
    float s0 = sq1[n], s1 = sq1[n_nodes + n];
    // aggregation: d = lane&15 (channel), j = lane>>4 (edge slot, 4-way)
    int d = lane & 15, j = lane >> 4;
    float a0 = 0.f, a1 = 0.f, ds = 0.f;
    for (int e = beg + j; e < end; e += 4) {
        int pk = sorted[e];
        int et = pk >> 16, s = pk & 0xFFFF;
        float w = __expf(lrelu((et ? s1 : s0) + sk1[et * n_nodes + s]));
        ds += w;
        float xv = x[s * IN_DIM + d];
        if (et == 0) a0 += w * xv; else a1 += w * xv;
    }
#pragma unroll
    for (int off = 16; off <= 32; off <<= 1) {
        a0 += __shfl_xor(a0, off);
        a1 += __shfl_xor(a1, off);
        ds += __shfl_xor(ds, off);
    }
    float inv = 1.f / (ds + 1e-16f);
    if (lane < 16) { Al[wid][lane] = a0 * inv; Al[wid][16 + lane] = a1 * inv; }
    // (same-wave LDS write->read; compiler inserts lgkmcnt wait)
    if (lane < 10) {
        float acc = Cl[lane];
#pragma unroll
        for (int dp = 0; dp < 32; ++dp) acc += Al[wid][dp] * Ml[dp * 10 + lane];
        int o = lane;
        if (o < 3)       xr2p[(size_t)n * 4 + o] = acc;
        else if (o < 6)  xr2p[((size_t)n_nodes + n) * 4 + (o - 3)] = acc;
        else if (o == 6) sq2[n] = acc;
        else if (o == 7) sq2[n_nodes + n] = acc;
        else if (o == 8) sk2[n] = acc;
        else             sk2[n_nodes + n] = acc;
    }
}

// ---------------- layer2 aggregation (16 lanes/node, single pass) -
__global__ void __launch_bounds__(256) k_node2(
    const int* __restrict__ offsets, const int* __restrict__ sorted,
    const float* __restrict__ sq2, const float* __restrict__ sk2,
    const float* __restrict__ xr2p, const float* __restrict__ b2,
    float* __restrict__ out, int n_nodes) {
    int gid = blockIdx.x * 256 + threadIdx.x;
    int n = gid >> 4;
    int l = threadIdx.x & 15;
    if (n >= n_nodes) return;
    int beg = offsets[n], end = offsets[n + 1];
    if (beg == end) {
        if (l < 3) out[(size_t)n * 3 + l] = b2[l];
        return;
    }
    float s0 = sq2[n], s1 = sq2[n_nodes + n];
    float lsum = 0.f, a0 = 0.f, a1 = 0.f, a2 = 0.f;
    for (int e = beg + l; e < end; e += 16) {
        int pk = sorted[e];
        int et = pk >> 16, s = pk & 0xFFFF;
        float w = __expf(lrelu((et ? s1 : s0) + sk2[et * n_nodes + s]));
        lsum += w;
        const float4 xr = *reinterpret_cast<const float4*>(xr2p + ((size_t)et * n_nodes + s) * 4);
        a0 += w * xr.x; a1 += w * xr.y; a2 += w * xr.z;
    }
#pragma unroll
    for (int off = 8; off; off >>= 1) {
        lsum += __shfl_xor(lsum, off);
        a0 += __shfl_xor(a0, off);
        a1 += __shfl_xor(a1, off);
        a2 += __shfl_xor(a2, off);
    }
    if (l == 0) {
        float inv = 1.f / (lsum + 1e-16f);
        out[(size_t)n * 3 + 0] = a0 * inv + b2[0];
        out[(size_t)n * 3 + 1] = a1 * inv + b2[1];
        out[(size_t)n * 3 + 2] = a2 * inv + b2[2];
    }
}

extern "C" void kernel_launch(void* const* d_in, const int* in_sizes, int n_in,
                              void* d_out, int out_size, void* d_ws, size_t ws_size,
                              hipStream_t stream) {
    const float* x  = (const float*)d_in[0];
    const int*   ei = (const int*)d_in[1];
    const int*   etp = (const int*)d_in[2];
    const float* W1 = (const float*)d_in[3];
    const float* q1 = (const float*)d_in[4];
    const float* k1 = (const float*)d_in[5];
    const float* b1 = (const float*)d_in[6];
    const float* W2 = (const float*)d_in[7];
    const float* q2 = (const float*)d_in[8];
    const float* k2 = (const float*)d_in[9];
    const float* b2 = (const float*)d_in[10];
    float* out = (float*)d_out;

    const int n_nodes = in_sizes[0] / IN_DIM;  // 50000
    const int ecnt    = in_sizes[2];           // 800000
    const int* srcp = ei;
    const int* dstp = ei + ecnt;

    char* wp = (char*)d_ws;
    auto alloc = [&](size_t bytes) -> char* {
        char* p = wp;
        wp += (bytes + 255) & ~(size_t)255;
        return p;
    };
    float* xr2p  = (float*)alloc((size_t)2 * n_nodes * 4 * 4);
    float* sq1   = (float*)alloc((size_t)2 * n_nodes * 4);
    float* sk1   = (float*)alloc((size_t)2 * n_nodes * 4);
    float* sq2   = (float*)alloc((size_t)2 * n_nodes * 4);
    float* sk2   = (float*)alloc((size_t)2 * n_nodes * 4);
    float* wq1   = (float*)alloc(32 * 4);
    float* wk1   = (float*)alloc(32 * 4);
    float* Mbuf  = (float*)alloc(320 * 4);
    float* Cbuf  = (float*)alloc(10 * 4);
    int* counts  = (int*)alloc((size_t)n_nodes * 4);
    int* exoff   = (int*)alloc((size_t)n_nodes * 4);
    int* blockSums = (int*)alloc(512);
    int* blockBase = (int*)alloc(512);
    int* offsets = (int*)alloc((size_t)(n_nodes + 1) * 4);
    int* rank    = (int*)alloc((size_t)ecnt * 4);
    int* sorted  = (int*)alloc((size_t)ecnt * 4);

    int nblk_scan = (n_nodes + 511) / 512;
    int eblk = (ecnt + 255) / 256;

    hipMemsetAsync(counts, 0, (size_t)n_nodes * 4, stream);

    k_pre<<<1, 512, 0, stream>>>(W1, q1, k1, b1, W2, q2, k2, wq1, wk1, Mbuf, Cbuf);
    k_prep<<<eblk, 256, 0, stream>>>(x, wq1, wk1, sq1, sk1, dstp, counts, rank, n_nodes, ecnt);
    k_scan1<<<nblk_scan, 512, 0, stream>>>(counts, exoff, blockSums, n_nodes);
    k_scan2<<<1, 128, 0, stream>>>(blockSums, blockBase, nblk_scan);
    k_scan3<<<(n_nodes + 256) / 256, 256, 0, stream>>>(exoff, blockBase, offsets, n_nodes, ecnt);
    k_scatter<<<eblk, 256, 0, stream>>>(srcp, dstp, etp, offsets, rank, sorted, ecnt);

    k_layer1<<<(n_nodes + 3) / 4, 256, 0, stream>>>(offsets, sorted, sq1, sk1, x, Mbuf, Cbuf,
                                                    xr2p, sq2, sk2, n_nodes);
    k_node2<<<(n_nodes * 16 + 255) / 256, 256, 0, stream>>>(offsets, sorted, sq2, sk2, xr2p, b2, out, n_nodes);
}